// Round 3
// baseline (543.242 us; speedup 1.0000x reference)
//
#include <hip/hip_runtime.h>
#include <hip/hip_bf16.h>

#define M_TOTAL (32 * 64 * 64)   // B*H*W = 131072 rows
#define CDIM 256
#define HDIM 1024

typedef float  floatx4 __attribute__((ext_vector_type(4)));
typedef short  short8  __attribute__((ext_vector_type(8)));

// ---------------------------------------------------------------------------
// Kernel 1: fused  x_new = x + LN1(x)  (stored bf16)  and  ln2 = LN2(x_new) bf16
// ---------------------------------------------------------------------------
__global__ __launch_bounds__(256) void ln_fused(
    const float* __restrict__ x,
    const float* __restrict__ g1, const float* __restrict__ b1,
    const float* __restrict__ g2, const float* __restrict__ b2,
    __hip_bfloat16* __restrict__ xnew, __hip_bfloat16* __restrict__ ln2o)
{
    const int  wave = threadIdx.x >> 6;
    const int  lane = threadIdx.x & 63;
    const long row  = (long)blockIdx.x * 4 + wave;

    const float4 v = ((const float4*)(x + row * CDIM))[lane];
    float s  = v.x + v.y + v.z + v.w;
    float sq = v.x * v.x + v.y * v.y + v.z * v.z + v.w * v.w;
#pragma unroll
    for (int o = 1; o < 64; o <<= 1) { s += __shfl_xor(s, o); sq += __shfl_xor(sq, o); }
    const float mu = s * (1.f / CDIM);
    const float rs = rsqrtf(sq * (1.f / CDIM) - mu * mu + 1e-5f);

    const float4 G1 = ((const float4*)g1)[lane];
    const float4 B1 = ((const float4*)b1)[lane];
    float4 xn;
    xn.x = v.x + (v.x - mu) * rs * G1.x + B1.x;
    xn.y = v.y + (v.y - mu) * rs * G1.y + B1.y;
    xn.z = v.z + (v.z - mu) * rs * G1.z + B1.z;
    xn.w = v.w + (v.w - mu) * rs * G1.w + B1.w;
    union { ushort4 u; __hip_bfloat16 h[4]; } ox;
    ox.h[0] = __float2bfloat16(xn.x); ox.h[1] = __float2bfloat16(xn.y);
    ox.h[2] = __float2bfloat16(xn.z); ox.h[3] = __float2bfloat16(xn.w);
    ((ushort4*)(xnew + row * CDIM))[lane] = ox.u;

    float s2 = xn.x + xn.y + xn.z + xn.w;
    float q2 = xn.x * xn.x + xn.y * xn.y + xn.z * xn.z + xn.w * xn.w;
#pragma unroll
    for (int o = 1; o < 64; o <<= 1) { s2 += __shfl_xor(s2, o); q2 += __shfl_xor(q2, o); }
    const float mu2 = s2 * (1.f / CDIM);
    const float rs2 = rsqrtf(q2 * (1.f / CDIM) - mu2 * mu2 + 1e-5f);

    const float4 G2 = ((const float4*)g2)[lane];
    const float4 B2 = ((const float4*)b2)[lane];
    union { ushort4 u; __hip_bfloat16 h[4]; } o4;
    o4.h[0] = __float2bfloat16((xn.x - mu2) * rs2 * G2.x + B2.x);
    o4.h[1] = __float2bfloat16((xn.y - mu2) * rs2 * G2.y + B2.y);
    o4.h[2] = __float2bfloat16((xn.z - mu2) * rs2 * G2.z + B2.z);
    o4.h[3] = __float2bfloat16((xn.w - mu2) * rs2 * G2.w + B2.w);
    ((ushort4*)(ln2o + row * CDIM))[lane] = o4.u;
}

// ---------------------------------------------------------------------------
// Kernel 2: transpose + fp32->bf16 convert.  src[R][Cc] f32 -> dst[Cc][R] bf16
// ---------------------------------------------------------------------------
__global__ __launch_bounds__(256) void transpose_cvt(
    const float* __restrict__ src, __hip_bfloat16* __restrict__ dst,
    int R, int Cc)
{
    const int idx = blockIdx.x * 256 + threadIdx.x;   // idx = c*R + r
    const int r = idx % R;
    const int c = idx / R;
    dst[idx] = __float2bfloat16(src[(long)r * Cc + c]);
}

// fast GELU (tanh form), max dev vs erf-GELU ~1e-3
__device__ __forceinline__ float gelu_fast(float v)
{
    const float t = v * __builtin_fmaf(v * v, 0.044715f, 1.0f);
    const float e = __expf(t * -1.5957691216f);
    return v * __builtin_amdgcn_rcpf(1.0f + e);
}

#define GLL(gp, lp)                                                           \
    __builtin_amdgcn_global_load_lds(                                         \
        (const __attribute__((address_space(1))) void*)(uintptr_t)(gp),       \
        (__attribute__((address_space(3))) void*)(unsigned)(uintptr_t)(lp),   \
        16, 0, 0)

// ---------------------------------------------------------------------------
// Kernel 3: bf16 MFMA GEMM, C = A[M][K]*Bt[N][K]^T, 128x128 tile, BK=64,
// 4 waves (2x2, 64x64 each), DOUBLE-BUFFERED 2-phase pipeline:
//   prologue stage(buf0); barrier
//   iter t: stage(buf^1, t+1)  [loads in flight]  -> compute(buf) -> barrier
// One barrier per K-step; compiler's vmcnt(0) drain lands AFTER the MFMAs.
// LDS layout per buffer/operand: [slot 0..7][row 0..127][8 bf16]; fragment
// reads are 256B-contiguous per quarter-wave (conflict-free, verified R2).
// EPI==0: bf16 GELU(acc+bias)            (fc1+GELU)
// EPI==1: f32 acc + bias + bf16 resid    (fc2+residual)
// ---------------------------------------------------------------------------
template<int KTOT, int EPI, int LOG2_TN>
__global__ __launch_bounds__(256) void gemm_bt(
    const __hip_bfloat16* __restrict__ A,
    const __hip_bfloat16* __restrict__ Bt,
    const float* __restrict__ bias,
    const __hip_bfloat16* __restrict__ resid,
    void* __restrict__ Cout, int Ncols)
{
    constexpr int NT = KTOT / 64;
    __shared__ __align__(16) __hip_bfloat16 As[2 * 8192];   // 32 KB
    __shared__ __align__(16) __hip_bfloat16 Bs[2 * 8192];   // 32 KB

    const int tid  = threadIdx.x;
    const int wave = tid >> 6;
    const int lane = tid & 63;

    // bijective XCD-aware swizzle (nwg % 8 == 0 for both grids)
    const int nwg  = gridDim.x * gridDim.y;
    const int flat = blockIdx.x + gridDim.x * blockIdx.y;
    const int l    = (flat & 7) * (nwg >> 3) + (flat >> 3);
    const int tn   = l & ((1 << LOG2_TN) - 1);
    const int tm   = l >> LOG2_TN;
    const long m0  = (long)tm * 128;
    const int  n0  = tn * 128;

    const int wr = (wave >> 1) * 64;
    const int wc = (wave & 1) * 64;
    const int fr = lane & 15;
    const int fq = lane >> 4;

    // staging: wave w, GLL p stages slot (2p + (w>>1)), rows (w&1)*64 + lane
    const __hip_bfloat16* gA = A  + (m0 + (wave & 1) * 64 + lane) * (long)KTOT + (wave >> 1) * 8;
    const __hip_bfloat16* gB = Bt + ((long)n0 + (wave & 1) * 64 + lane) * KTOT + (wave >> 1) * 8;
    const int wseg = wave * 512;

    floatx4 acc[4][4] = {};

    auto stage = [&](int bi, int koff) {
#pragma unroll
        for (int p = 0; p < 4; ++p) {
            GLL(gA + koff + p * 16, As + bi * 8192 + wseg + p * 2048);
            GLL(gB + koff + p * 16, Bs + bi * 8192 + wseg + p * 2048);
        }
    };
    auto compute = [&](int bi) {
        const __hip_bfloat16* baseA = As + bi * 8192 + fq * 1024 + (wr + fr) * 8;
        const __hip_bfloat16* baseB = Bs + bi * 8192 + fq * 1024 + (wc + fr) * 8;
        short8 af[2][4], bg[2][4];
#pragma unroll
        for (int s = 0; s < 2; ++s)
#pragma unroll
            for (int m = 0; m < 4; ++m) {
                af[s][m] = *(const short8*)(baseA + s * 4096 + m * 128);
                bg[s][m] = *(const short8*)(baseB + s * 4096 + m * 128);
            }
#pragma unroll
        for (int s = 0; s < 2; ++s)
#pragma unroll
            for (int m = 0; m < 4; ++m)
#pragma unroll
                for (int n = 0; n < 4; ++n)
                    acc[m][n] = __builtin_amdgcn_mfma_f32_16x16x32_bf16(
                        af[s][m], bg[s][n], acc[m][n], 0, 0, 0);
    };

    stage(0, 0);
    __syncthreads();                    // prologue drain
#pragma unroll
    for (int t = 0; t < NT - 1; ++t) {
        stage((t + 1) & 1, (t + 1) * 64);   // next tile: loads fly during compute
        compute(t & 1);
        __syncthreads();                    // vmcnt(0)+lgkmcnt(0) drain here
    }
    compute((NT - 1) & 1);

    // Epilogue.  C/D layout: col = lane&15, row = (lane>>4)*4 + reg
    float bb[4];
#pragma unroll
    for (int n = 0; n < 4; ++n) bb[n] = bias[n0 + wc + n * 16 + fr];

    if (EPI == 0) {
        __hip_bfloat16* Cb = (__hip_bfloat16*)Cout;
#pragma unroll
        for (int m = 0; m < 4; ++m) {
            const long rbase = m0 + wr + m * 16 + fq * 4;
#pragma unroll
            for (int n = 0; n < 4; ++n) {
                const int col = n0 + wc + n * 16 + fr;
#pragma unroll
                for (int j = 0; j < 4; ++j) {
                    const float v = acc[m][n][j] + bb[n];
                    Cb[(rbase + j) * Ncols + col] = __float2bfloat16(gelu_fast(v));
                }
            }
        }
    } else {
        float* Cf = (float*)Cout;
#pragma unroll
        for (int m = 0; m < 4; ++m) {
            const long rbase = m0 + wr + m * 16 + fq * 4;
#pragma unroll
            for (int n = 0; n < 4; ++n) {
                const int col = n0 + wc + n * 16 + fr;
#pragma unroll
                for (int j = 0; j < 4; ++j) {
                    const float r = __bfloat162float(resid[(rbase + j) * Ncols + col]);
                    Cf[(rbase + j) * Ncols + col] = acc[m][n][j] + bb[n] + r;
                }
            }
        }
    }
}

// ---------------------------------------------------------------------------
extern "C" void kernel_launch(void* const* d_in, const int* in_sizes, int n_in,
                              void* d_out, int out_size, void* d_ws, size_t ws_size,
                              hipStream_t stream)
{
    const float* x    = (const float*)d_in[0];
    const float* ln1g = (const float*)d_in[1];
    const float* ln1b = (const float*)d_in[2];
    const float* ln2g = (const float*)d_in[3];
    const float* ln2b = (const float*)d_in[4];
    const float* w1   = (const float*)d_in[5];
    const float* b1   = (const float*)d_in[6];
    const float* w2   = (const float*)d_in[7];
    const float* b2   = (const float*)d_in[8];
    float* out = (float*)d_out;

    // workspace layout (bytes)
    char* ws = (char*)d_ws;
    __hip_bfloat16* xnew = (__hip_bfloat16*)ws;                        //  67,108,864
    __hip_bfloat16* ln2o = (__hip_bfloat16*)(ws + 67108864);           //  67,108,864
    __hip_bfloat16* act  = (__hip_bfloat16*)(ws + 134217728);          // 268,435,456
    __hip_bfloat16* w1t  = (__hip_bfloat16*)(ws + 402653184);          //     524,288
    __hip_bfloat16* w2t  = (__hip_bfloat16*)(ws + 403177472);          //     524,288

    // 1) fused LN1-residual + LN2
    ln_fused<<<M_TOTAL / 4, 256, 0, stream>>>(x, ln1g, ln1b, ln2g, ln2b, xnew, ln2o);

    // 2) weight transpose + bf16 convert
    transpose_cvt<<<(CDIM * HDIM) / 256, 256, 0, stream>>>(w1, w1t, CDIM, HDIM); // w1t[1024][256]
    transpose_cvt<<<(CDIM * HDIM) / 256, 256, 0, stream>>>(w2, w2t, HDIM, CDIM); // w2t[256][1024]

    // 3) fc1 + GELU :  act[M][1024] = GELU(ln2o[M][256] @ w1 + b1)
    gemm_bt<CDIM, 0, 3><<<dim3(HDIM / 128, M_TOTAL / 128), 256, 0, stream>>>(
        ln2o, w1t, b1, nullptr, (void*)act, HDIM);

    // 4) fc2 + residual :  out[M][256] = act @ w2 + b2 + xnew
    gemm_bt<HDIM, 1, 1><<<dim3(CDIM / 128, M_TOTAL / 128), 256, 0, stream>>>(
        act, w2t, b2, xnew, (void*)out, CDIM);
}

// Round 4
// 421.884 us; speedup vs baseline: 1.2877x; 1.2877x over previous
//
#include <hip/hip_runtime.h>
#include <hip/hip_bf16.h>

#define M_TOTAL (32 * 64 * 64)   // 131072 rows
#define CDIM 256
#define HDIM 1024

typedef float  floatx4 __attribute__((ext_vector_type(4)));
typedef short  short8  __attribute__((ext_vector_type(8)));

// ---------------------------------------------------------------------------
// transpose + fp32->bf16 convert.  src[R][Cc] f32 -> dst[Cc][R] bf16
// ---------------------------------------------------------------------------
__global__ __launch_bounds__(256) void transpose_cvt(
    const float* __restrict__ src, __hip_bfloat16* __restrict__ dst,
    int R, int Cc)
{
    const int idx = blockIdx.x * 256 + threadIdx.x;   // idx = c*R + r
    const int r = idx % R;
    const int c = idx / R;
    dst[idx] = __float2bfloat16(src[(long)r * Cc + c]);
}

// fast GELU (tanh form), max dev vs erf-GELU ~1e-3 (validated R2: absmax 0.0625)
__device__ __forceinline__ float gelu_fast(float v)
{
    const float t = v * __builtin_fmaf(v * v, 0.044715f, 1.0f);
    const float e = __expf(t * -1.5957691216f);
    return v * __builtin_amdgcn_rcpf(1.0f + e);
}

// ---------------------------------------------------------------------------
// Fully fused Swin block (attention path is identity):
//   xn  = x + LN1(x)                       (bf16 -> xnbuf, global round-trip)
//   ln2 = LN2(xn)                          (bf16 -> LDS As, frag layout)
//   hid = GELU(ln2 @ w1 + b1)              (per 256-col chunk -> LDS Hs)
//   out = xn + hid @ w2 + b2               (acc2 accumulated across chunks)
//
// Block: 128 rows, 512 threads (8 waves = 2 row-groups x 4 col-groups).
// LDS: As 64KB ([kf][slot][row][8] frag layout) + Hs 64KB (same layout).
// B operands (w1t/w2t, 1MB bf16 total) are read per-fragment from global —
// L2-resident per XCD, no LDS staging, no staging barriers.
// Verified conventions: A/B frags share k-map (kf*32 + fq*8 + e, row/col=fr);
// C/D layout col=lane&15, row=(lane>>4)*4+reg (m89, R1-R3 passed).
// ---------------------------------------------------------------------------
__global__ __launch_bounds__(512) void swin_fused(
    const float* __restrict__ x,
    const float* __restrict__ ln1g, const float* __restrict__ ln1b,
    const float* __restrict__ ln2g, const float* __restrict__ ln2b,
    const __hip_bfloat16* __restrict__ w1t, const float* __restrict__ fb1,
    const __hip_bfloat16* __restrict__ w2t, const float* __restrict__ fb2,
    __hip_bfloat16* __restrict__ xnbuf, float* __restrict__ out)
{
    __shared__ __align__(16) __hip_bfloat16 As[32768];  // 64 KB
    __shared__ __align__(16) __hip_bfloat16 Hs[32768];  // 64 KB

    const int  tid = threadIdx.x;
    const long m0  = (long)blockIdx.x * 128;

    // ---------------- LN phase: 4 threads per row (quad) ----------------
    {
        const int row  = tid >> 2;        // 0..127
        const int part = tid & 3;         // 64-element segment
        const float* xr = x + (m0 + row) * CDIM + part * 64;

        float4 v[16];
        float s = 0.f, sq = 0.f;
#pragma unroll
        for (int i = 0; i < 16; ++i) {
            v[i] = ((const float4*)xr)[i];
            s  += v[i].x + v[i].y + v[i].z + v[i].w;
            sq += v[i].x*v[i].x + v[i].y*v[i].y + v[i].z*v[i].z + v[i].w*v[i].w;
        }
        s  += __shfl_xor(s, 1);  s  += __shfl_xor(s, 2);
        sq += __shfl_xor(sq, 1); sq += __shfl_xor(sq, 2);
        const float mu = s * (1.f / CDIM);
        const float rs = rsqrtf(sq * (1.f / CDIM) - mu * mu + 1e-5f);

        // xn = x + LN1(x), overwrite v; accumulate LN2 stats; store xnbuf bf16
        float s2 = 0.f, q2 = 0.f;
        __hip_bfloat16* xnp = xnbuf + (m0 + row) * CDIM + part * 64;
#pragma unroll
        for (int i = 0; i < 16; ++i) {
            const float4 G = ((const float4*)(ln1g + part * 64))[i];
            const float4 B = ((const float4*)(ln1b + part * 64))[i];
            v[i].x += (v[i].x - mu) * rs * G.x + B.x;
            v[i].y += (v[i].y - mu) * rs * G.y + B.y;
            v[i].z += (v[i].z - mu) * rs * G.z + B.z;
            v[i].w += (v[i].w - mu) * rs * G.w + B.w;
            s2 += v[i].x + v[i].y + v[i].z + v[i].w;
            q2 += v[i].x*v[i].x + v[i].y*v[i].y + v[i].z*v[i].z + v[i].w*v[i].w;
            union { ushort4 u; __hip_bfloat16 h[4]; } p;
            p.h[0] = __float2bfloat16(v[i].x); p.h[1] = __float2bfloat16(v[i].y);
            p.h[2] = __float2bfloat16(v[i].z); p.h[3] = __float2bfloat16(v[i].w);
            ((ushort4*)xnp)[i] = p.u;
        }
        s2 += __shfl_xor(s2, 1); s2 += __shfl_xor(s2, 2);
        q2 += __shfl_xor(q2, 1); q2 += __shfl_xor(q2, 2);
        const float mu2 = s2 * (1.f / CDIM);
        const float rs2 = rsqrtf(q2 * (1.f / CDIM) - mu2 * mu2 + 1e-5f);

        // ln2 -> As in fragment layout: As[((col>>5)*4 + ((col>>3)&3))*128 + row]
#pragma unroll
        for (int i = 0; i < 16; ++i) {
            const int col0 = part * 64 + i * 4;
            const float4 G = ((const float4*)(ln2g + part * 64))[i];
            const float4 B = ((const float4*)(ln2b + part * 64))[i];
            union { ushort4 u; __hip_bfloat16 h[4]; } p;
            p.h[0] = __float2bfloat16((v[i].x - mu2) * rs2 * G.x + B.x);
            p.h[1] = __float2bfloat16((v[i].y - mu2) * rs2 * G.y + B.y);
            p.h[2] = __float2bfloat16((v[i].z - mu2) * rs2 * G.z + B.z);
            p.h[3] = __float2bfloat16((v[i].w - mu2) * rs2 * G.w + B.w);
            const int idx16 = ((col0 >> 5) * 4 + ((col0 >> 3) & 3)) * 128 + row;
            *(ushort4*)(As + idx16 * 8 + (col0 & 7)) = p.u;
        }
    }
    __syncthreads();

    // ---------------- MLP phase ----------------
    const int wave = tid >> 6, lane = tid & 63;
    const int wm = wave >> 2, wn = wave & 3;       // 2 row-groups x 4 col-groups
    const int rm = wm * 64;
    const int fr = lane & 15, fq = lane >> 4;

    floatx4 acc2[4][4] = {};

    for (int c = 0; c < 4; ++c) {                  // 4 chunks of 256 hidden cols
        // ---- fc1: hid_chunk[128][256] = ln2 @ w1[:, chunk] ----
        const int nc0 = c * 256 + wn * 64;         // this wave's 64 hidden cols
        floatx4 acc1[4][4] = {};
#pragma unroll
        for (int kf = 0; kf < 8; ++kf) {
            short8 a[4], b[4];
#pragma unroll
            for (int mf = 0; mf < 4; ++mf)
                a[mf] = *(const short8*)(As + ((kf*4 + fq)*128 + rm + mf*16 + fr)*8);
#pragma unroll
            for (int nf = 0; nf < 4; ++nf)
                b[nf] = *(const short8*)(w1t + (long)(nc0 + nf*16 + fr)*CDIM + kf*32 + fq*8);
#pragma unroll
            for (int mf = 0; mf < 4; ++mf)
#pragma unroll
                for (int nf = 0; nf < 4; ++nf)
                    acc1[mf][nf] = __builtin_amdgcn_mfma_f32_16x16x32_bf16(
                        a[mf], b[nf], acc1[mf][nf], 0, 0, 0);
        }
        // GELU + bias -> Hs (fragment layout, within-chunk col)
#pragma unroll
        for (int nf = 0; nf < 4; ++nf) {
            const int   col    = wn * 64 + nf * 16 + fr;     // 0..255 in chunk
            const float bb     = fb1[c * 256 + col];
            const int   base16 = ((col >> 5) * 4 + ((col >> 3) & 3)) * 128;
            const int   e      = col & 7;
#pragma unroll
            for (int mf = 0; mf < 4; ++mf)
#pragma unroll
                for (int j = 0; j < 4; ++j) {
                    const int row = rm + mf * 16 + fq * 4 + j;
                    Hs[(base16 + row) * 8 + e] =
                        __float2bfloat16(gelu_fast(acc1[mf][nf][j] + bb));
                }
        }
        __syncthreads();   // hid chunk visible to all waves

        // ---- fc2 partial: acc2 += hid_chunk @ w2[chunk, :] ----
#pragma unroll
        for (int kf = 0; kf < 8; ++kf) {
            short8 a[4], b[4];
#pragma unroll
            for (int mf = 0; mf < 4; ++mf)
                a[mf] = *(const short8*)(Hs + ((kf*4 + fq)*128 + rm + mf*16 + fr)*8);
#pragma unroll
            for (int nf = 0; nf < 4; ++nf)
                b[nf] = *(const short8*)(w2t + (long)(wn*64 + nf*16 + fr)*HDIM + c*256 + kf*32 + fq*8);
#pragma unroll
            for (int mf = 0; mf < 4; ++mf)
#pragma unroll
                for (int nf = 0; nf < 4; ++nf)
                    acc2[mf][nf] = __builtin_amdgcn_mfma_f32_16x16x32_bf16(
                        a[mf], b[nf], acc2[mf][nf], 0, 0, 0);
        }
        __syncthreads();   // Hs reads done before next chunk overwrites
    }

    // ---------------- epilogue: out = acc2 + b2 + xn ----------------
#pragma unroll
    for (int nf = 0; nf < 4; ++nf) {
        const int   oc = wn * 64 + nf * 16 + fr;
        const float bb = fb2[oc];
#pragma unroll
        for (int mf = 0; mf < 4; ++mf)
#pragma unroll
            for (int j = 0; j < 4; ++j) {
                const long row = m0 + rm + mf * 16 + fq * 4 + j;
                out[row * CDIM + oc] = acc2[mf][nf][j] + bb
                                     + __bfloat162float(xnbuf[row * CDIM + oc]);
            }
    }
}

// ---------------------------------------------------------------------------
extern "C" void kernel_launch(void* const* d_in, const int* in_sizes, int n_in,
                              void* d_out, int out_size, void* d_ws, size_t ws_size,
                              hipStream_t stream)
{
    const float* x    = (const float*)d_in[0];
    const float* ln1g = (const float*)d_in[1];
    const float* ln1b = (const float*)d_in[2];
    const float* ln2g = (const float*)d_in[3];
    const float* ln2b = (const float*)d_in[4];
    const float* w1   = (const float*)d_in[5];
    const float* b1   = (const float*)d_in[6];
    const float* w2   = (const float*)d_in[7];
    const float* b2   = (const float*)d_in[8];
    float* out = (float*)d_out;

    // workspace
    char* ws = (char*)d_ws;
    __hip_bfloat16* xnbuf = (__hip_bfloat16*)ws;                 //  67,108,864 B
    __hip_bfloat16* w1t   = (__hip_bfloat16*)(ws + 67108864);    //     524,288 B
    __hip_bfloat16* w2t   = (__hip_bfloat16*)(ws + 67633152);    //     524,288 B

    // weight transpose + bf16 convert (w1t[1024][256], w2t[256][1024])
    transpose_cvt<<<(CDIM * HDIM) / 256, 256, 0, stream>>>(w1, w1t, CDIM, HDIM);
    transpose_cvt<<<(CDIM * HDIM) / 256, 256, 0, stream>>>(w2, w2t, HDIM, CDIM);

    // fully fused block
    swin_fused<<<M_TOTAL / 128, 512, 0, stream>>>(
        x, ln1g, ln1b, ln2g, ln2b, w1t, b1, w2t, b2, xnbuf, out);
}

// Round 5
// 418.838 us; speedup vs baseline: 1.2970x; 1.0073x over previous
//
#include <hip/hip_runtime.h>
#include <hip/hip_bf16.h>

#define M_TOTAL (32 * 64 * 64)   // 131072 rows
#define CDIM 256
#define HDIM 1024

typedef float  floatx4 __attribute__((ext_vector_type(4)));
typedef short  short8  __attribute__((ext_vector_type(8)));

// ---------------------------------------------------------------------------
// transpose + fp32->bf16 convert.  src[R][Cc] f32 -> dst[Cc][R] bf16
// ---------------------------------------------------------------------------
__global__ __launch_bounds__(256) void transpose_cvt(
    const float* __restrict__ src, __hip_bfloat16* __restrict__ dst,
    int R, int Cc)
{
    const int idx = blockIdx.x * 256 + threadIdx.x;   // idx = c*R + r
    const int r = idx % R;
    const int c = idx / R;
    dst[idx] = __float2bfloat16(src[(long)r * Cc + c]);
}

// fast GELU (tanh form), max dev vs erf-GELU ~1e-3 (validated: absmax 0.0625)
__device__ __forceinline__ float gelu_fast(float v)
{
    const float t = v * __builtin_fmaf(v * v, 0.044715f, 1.0f);
    const float e = __expf(t * -1.5957691216f);
    return v * __builtin_amdgcn_rcpf(1.0f + e);
}

// ---------------------------------------------------------------------------
// Fully fused Swin block (attention path is identity):
//   xn  = x + LN1(x)   (bf16 -> xnbuf)
//   ln2 = LN2(xn)      (bf16 -> LDS As, fragment layout)
//   for c in 0..7 (hidden chunks of 128):
//     fc1: hid = GELU(ln2 @ w1[:,c] + b1)  -> Hs[c&1]   (burst-loaded w1 frags)
//     barrier
//     fc2: acc2 += hid @ w2[c,:]                        (burst-loaded w2 frags)
//   out = xn + acc2 + b2
//
// 1024 blocks x 512 thr (8 waves = 2 row-groups x 4 col-groups), M-tile 128.
// LDS: As 64KB + Hs 2x32KB = 128KB. One barrier per chunk; Hs double-buffered
// so fc1(c+1) overlaps fc2(c) in the same barrier-free region.
// Verified conventions (R1-R4): A/B frags lane(fq,fr) reg e <-> [fr][fq*8+e];
// C/D: col=lane&15, row=(lane>>4)*4+reg.
// ---------------------------------------------------------------------------
__global__ __launch_bounds__(512, 2) void swin_fused(
    const float* __restrict__ x,
    const float* __restrict__ ln1g, const float* __restrict__ ln1b,
    const float* __restrict__ ln2g, const float* __restrict__ ln2b,
    const __hip_bfloat16* __restrict__ w1t, const float* __restrict__ fb1,
    const __hip_bfloat16* __restrict__ w2t, const float* __restrict__ fb2,
    __hip_bfloat16* __restrict__ xnbuf, float* __restrict__ out)
{
    __shared__ __align__(16) __hip_bfloat16 As[32768];      // 64 KB
    __shared__ __align__(16) __hip_bfloat16 Hs[2][16384];   // 2 x 32 KB

    const int  tid = threadIdx.x;
    const long m0  = (long)blockIdx.x * 128;

    // ---------------- LN phase: 4 threads per row ----------------
    {
        const int row  = tid >> 2;        // 0..127
        const int part = tid & 3;         // 64-element segment
        const float* xr = x + (m0 + row) * CDIM + part * 64;

        float4 v[16];
        float s = 0.f, sq = 0.f;
#pragma unroll
        for (int i = 0; i < 16; ++i) {
            v[i] = ((const float4*)xr)[i];
            s  += v[i].x + v[i].y + v[i].z + v[i].w;
            sq += v[i].x*v[i].x + v[i].y*v[i].y + v[i].z*v[i].z + v[i].w*v[i].w;
        }
        s  += __shfl_xor(s, 1);  s  += __shfl_xor(s, 2);
        sq += __shfl_xor(sq, 1); sq += __shfl_xor(sq, 2);
        const float mu = s * (1.f / CDIM);
        const float rs = rsqrtf(sq * (1.f / CDIM) - mu * mu + 1e-5f);

        float s2 = 0.f, q2 = 0.f;
        __hip_bfloat16* xnp = xnbuf + (m0 + row) * CDIM + part * 64;
#pragma unroll
        for (int i = 0; i < 16; ++i) {
            const float4 G = ((const float4*)(ln1g + part * 64))[i];
            const float4 B = ((const float4*)(ln1b + part * 64))[i];
            v[i].x += (v[i].x - mu) * rs * G.x + B.x;
            v[i].y += (v[i].y - mu) * rs * G.y + B.y;
            v[i].z += (v[i].z - mu) * rs * G.z + B.z;
            v[i].w += (v[i].w - mu) * rs * G.w + B.w;
            s2 += v[i].x + v[i].y + v[i].z + v[i].w;
            q2 += v[i].x*v[i].x + v[i].y*v[i].y + v[i].z*v[i].z + v[i].w*v[i].w;
            union { ushort4 u; __hip_bfloat16 h[4]; } p;
            p.h[0] = __float2bfloat16(v[i].x); p.h[1] = __float2bfloat16(v[i].y);
            p.h[2] = __float2bfloat16(v[i].z); p.h[3] = __float2bfloat16(v[i].w);
            ((ushort4*)xnp)[i] = p.u;
        }
        s2 += __shfl_xor(s2, 1); s2 += __shfl_xor(s2, 2);
        q2 += __shfl_xor(q2, 1); q2 += __shfl_xor(q2, 2);
        const float mu2 = s2 * (1.f / CDIM);
        const float rs2 = rsqrtf(q2 * (1.f / CDIM) - mu2 * mu2 + 1e-5f);

        // ln2 -> As fragment layout: elem idx = ((k>>5)*4+((k>>3)&3))*1024 + row*8 + (k&7)
#pragma unroll
        for (int i = 0; i < 16; ++i) {
            const int col0 = part * 64 + i * 4;
            const float4 G = ((const float4*)(ln2g + part * 64))[i];
            const float4 B = ((const float4*)(ln2b + part * 64))[i];
            union { ushort4 u; __hip_bfloat16 h[4]; } p;
            p.h[0] = __float2bfloat16((v[i].x - mu2) * rs2 * G.x + B.x);
            p.h[1] = __float2bfloat16((v[i].y - mu2) * rs2 * G.y + B.y);
            p.h[2] = __float2bfloat16((v[i].z - mu2) * rs2 * G.z + B.z);
            p.h[3] = __float2bfloat16((v[i].w - mu2) * rs2 * G.w + B.w);
            const int idx16 = ((col0 >> 5) * 4 + ((col0 >> 3) & 3)) * 128 + row;
            *(ushort4*)(As + idx16 * 8 + (col0 & 7)) = p.u;
        }
    }
    __syncthreads();

    // ---------------- MLP phase ----------------
    const int wave = tid >> 6, lane = tid & 63;
    const int wm = wave >> 2, wn = wave & 3;   // 2 row-groups x 4 col-groups
    const int fr = lane & 15, fq = lane >> 4;

    floatx4 acc2[4][4] = {};

#pragma unroll 2
    for (int c = 0; c < 8; ++c) {
        __hip_bfloat16* hb = Hs[c & 1];

        // ---- fc1: burst-load w1 frags, then LDS+MFMA ----
        short8 b1f[8][2];
#pragma unroll
        for (int kf = 0; kf < 8; ++kf)
#pragma unroll
            for (int nf = 0; nf < 2; ++nf)
                b1f[kf][nf] = *(const short8*)(
                    w1t + (c * 128 + wn * 32 + nf * 16 + fr) * 256 + kf * 32 + fq * 8);

        floatx4 acc1[4][2] = {};
#pragma unroll
        for (int kf = 0; kf < 8; ++kf) {
            short8 a[4];
#pragma unroll
            for (int mf = 0; mf < 4; ++mf)
                a[mf] = *(const short8*)(
                    As + ((kf * 4 + fq) * 128 + wm * 64 + mf * 16 + fr) * 8);
#pragma unroll
            for (int mf = 0; mf < 4; ++mf)
#pragma unroll
                for (int nf = 0; nf < 2; ++nf)
                    acc1[mf][nf] = __builtin_amdgcn_mfma_f32_16x16x32_bf16(
                        a[mf], b1f[kf][nf], acc1[mf][nf], 0, 0, 0);
        }

        // GELU + bias -> Hs[c&1] (fragment layout, in-chunk col)
#pragma unroll
        for (int nf = 0; nf < 2; ++nf) {
            const int   col = wn * 32 + nf * 16 + fr;        // 0..127 in chunk
            const float bb  = fb1[c * 128 + col];
            __hip_bfloat16* hp = hb + ((col >> 5) * 4 + ((col >> 3) & 3)) * 1024 + (col & 7);
#pragma unroll
            for (int mf = 0; mf < 4; ++mf)
#pragma unroll
                for (int j = 0; j < 4; ++j) {
                    const int row = wm * 64 + mf * 16 + fq * 4 + j;
                    hp[row * 8] = __float2bfloat16(gelu_fast(acc1[mf][nf][j] + bb));
                }
        }
        __syncthreads();   // Hs[c&1] complete; Hs[(c+1)&1] free to overwrite

        // ---- fc2 partial: burst-load w2 frags, then LDS+MFMA ----
        short8 b2f[4][4];
#pragma unroll
        for (int kf = 0; kf < 4; ++kf)
#pragma unroll
            for (int nf = 0; nf < 4; ++nf)
                b2f[kf][nf] = *(const short8*)(
                    w2t + (wn * 64 + nf * 16 + fr) * 1024 + c * 128 + kf * 32 + fq * 8);
#pragma unroll
        for (int kf = 0; kf < 4; ++kf) {
            short8 ha[4];
#pragma unroll
            for (int mf = 0; mf < 4; ++mf)
                ha[mf] = *(const short8*)(
                    hb + ((kf * 4 + fq) * 128 + wm * 64 + mf * 16 + fr) * 8);
#pragma unroll
            for (int mf = 0; mf < 4; ++mf)
#pragma unroll
                for (int nf = 0; nf < 4; ++nf)
                    acc2[mf][nf] = __builtin_amdgcn_mfma_f32_16x16x32_bf16(
                        ha[mf], b2f[kf][nf], acc2[mf][nf], 0, 0, 0);
        }
    }

    // ---------------- epilogue: out = acc2 + b2 + xn ----------------
#pragma unroll
    for (int nf = 0; nf < 4; ++nf) {
        const int   oc = wn * 64 + nf * 16 + fr;
        const float bb = fb2[oc];
#pragma unroll
        for (int mf = 0; mf < 4; ++mf)
#pragma unroll
            for (int j = 0; j < 4; ++j) {
                const long row = m0 + wm * 64 + mf * 16 + fq * 4 + j;
                out[row * CDIM + oc] = acc2[mf][nf][j] + bb
                                     + __bfloat162float(xnbuf[row * CDIM + oc]);
            }
    }
}

// ---------------------------------------------------------------------------
extern "C" void kernel_launch(void* const* d_in, const int* in_sizes, int n_in,
                              void* d_out, int out_size, void* d_ws, size_t ws_size,
                              hipStream_t stream)
{
    const float* x    = (const float*)d_in[0];
    const float* ln1g = (const float*)d_in[1];
    const float* ln1b = (const float*)d_in[2];
    const float* ln2g = (const float*)d_in[3];
    const float* ln2b = (const float*)d_in[4];
    const float* w1   = (const float*)d_in[5];
    const float* b1   = (const float*)d_in[6];
    const float* w2   = (const float*)d_in[7];
    const float* b2   = (const float*)d_in[8];
    float* out = (float*)d_out;

    // workspace
    char* ws = (char*)d_ws;
    __hip_bfloat16* xnbuf = (__hip_bfloat16*)ws;                 //  67,108,864 B
    __hip_bfloat16* w1t   = (__hip_bfloat16*)(ws + 67108864);    //     524,288 B
    __hip_bfloat16* w2t   = (__hip_bfloat16*)(ws + 67633152);    //     524,288 B

    // weight transpose + bf16 convert (w1t[1024][256], w2t[256][1024])
    transpose_cvt<<<(CDIM * HDIM) / 256, 256, 0, stream>>>(w1, w1t, CDIM, HDIM);
    transpose_cvt<<<(CDIM * HDIM) / 256, 256, 0, stream>>>(w2, w2t, HDIM, CDIM);

    // fully fused block
    swin_fused<<<M_TOTAL / 128, 512, 0, stream>>>(
        x, ln1g, ln1b, ln2g, ln2b, w1t, b1, w2t, b2, xnbuf, out);
}

// Round 6
// 378.812 us; speedup vs baseline: 1.4341x; 1.1057x over previous
//
#include <hip/hip_runtime.h>
#include <hip/hip_bf16.h>

#define M_TOTAL (32 * 64 * 64)   // 131072 rows
#define CDIM 256
#define HDIM 1024

typedef float  floatx4 __attribute__((ext_vector_type(4)));
typedef short  short8  __attribute__((ext_vector_type(8)));

// ---------------------------------------------------------------------------
// transpose + fp32->bf16 convert.  src[R][Cc] f32 -> dst[Cc][R] bf16
// ---------------------------------------------------------------------------
__global__ __launch_bounds__(256) void transpose_cvt(
    const float* __restrict__ src, __hip_bfloat16* __restrict__ dst,
    int R, int Cc)
{
    const int idx = blockIdx.x * 256 + threadIdx.x;   // idx = c*R + r
    const int r = idx % R;
    const int c = idx / R;
    dst[idx] = __float2bfloat16(src[(long)r * Cc + c]);
}

// fast GELU (tanh form), max dev vs erf-GELU ~1e-3 (validated: absmax 0.0625)
__device__ __forceinline__ float gelu_fast(float v)
{
    const float t = v * __builtin_fmaf(v * v, 0.044715f, 1.0f);
    const float e = __expf(t * -1.5957691216f);
    return v * __builtin_amdgcn_rcpf(1.0f + e);
}

// ---------------------------------------------------------------------------
// Fully fused Swin block (attention path = identity), software-pipelined:
//   xn  = x + LN1(x)  (bf16 -> xnbuf) ;  ln2 = LN2(xn) (bf16 -> LDS As)
//   8 hidden chunks of 128:
//     iter c: issue w1-frags(c); fc2(c-1); fc1(c); GELU->Hs[c&1];
//             issue w2-frags(c); barrier
//   out = xn + acc2 + b2
// sched_barrier(0) after each load burst pins the loads (compiler cannot
// sink them back to just-in-time — the R3/R4/R5 identical-perf failure).
// Plain global->reg loads stay in flight across s_barrier (no vmcnt drain);
// first use in the NEXT phase gives a counted vmcnt wait (T4 pattern).
// LDS: As 64KB + Hs 2x32KB = 128KB, 1 block/CU, 8 waves (2 rg x 4 cg).
// Verified conventions (R1-R5): frag k-map slot=kf*4+fq, elem k&7, row/col=fr;
// C/D: col=lane&15, row=(lane>>4)*4+reg.
// ---------------------------------------------------------------------------
__global__ __launch_bounds__(512) void swin_fused(
    const float* __restrict__ x,
    const float* __restrict__ ln1g, const float* __restrict__ ln1b,
    const float* __restrict__ ln2g, const float* __restrict__ ln2b,
    const __hip_bfloat16* __restrict__ w1t, const float* __restrict__ fb1,
    const __hip_bfloat16* __restrict__ w2t, const float* __restrict__ fb2,
    __hip_bfloat16* __restrict__ xnbuf, float* __restrict__ out)
{
    __shared__ __align__(16) __hip_bfloat16 As[32768];      // 64 KB
    __shared__ __align__(16) __hip_bfloat16 Hs[2][16384];   // 2 x 32 KB

    const int  tid = threadIdx.x;
    const long m0  = (long)blockIdx.x * 128;

    // ---------------- LN phase: 4 threads per row ----------------
    {
        const int row  = tid >> 2;        // 0..127
        const int part = tid & 3;         // 64-element segment
        const float* xr = x + (m0 + row) * CDIM + part * 64;

        float4 v[16];
        float s = 0.f, sq = 0.f;
#pragma unroll
        for (int i = 0; i < 16; ++i) {
            v[i] = ((const float4*)xr)[i];
            s  += v[i].x + v[i].y + v[i].z + v[i].w;
            sq += v[i].x*v[i].x + v[i].y*v[i].y + v[i].z*v[i].z + v[i].w*v[i].w;
        }
        s  += __shfl_xor(s, 1);  s  += __shfl_xor(s, 2);
        sq += __shfl_xor(sq, 1); sq += __shfl_xor(sq, 2);
        const float mu = s * (1.f / CDIM);
        const float rs = rsqrtf(sq * (1.f / CDIM) - mu * mu + 1e-5f);

        float s2 = 0.f, q2 = 0.f;
        __hip_bfloat16* xnp = xnbuf + (m0 + row) * CDIM + part * 64;
#pragma unroll
        for (int i = 0; i < 16; ++i) {
            const float4 G = ((const float4*)(ln1g + part * 64))[i];
            const float4 B = ((const float4*)(ln1b + part * 64))[i];
            v[i].x += (v[i].x - mu) * rs * G.x + B.x;
            v[i].y += (v[i].y - mu) * rs * G.y + B.y;
            v[i].z += (v[i].z - mu) * rs * G.z + B.z;
            v[i].w += (v[i].w - mu) * rs * G.w + B.w;
            s2 += v[i].x + v[i].y + v[i].z + v[i].w;
            q2 += v[i].x*v[i].x + v[i].y*v[i].y + v[i].z*v[i].z + v[i].w*v[i].w;
            union { ushort4 u; __hip_bfloat16 h[4]; } p;
            p.h[0] = __float2bfloat16(v[i].x); p.h[1] = __float2bfloat16(v[i].y);
            p.h[2] = __float2bfloat16(v[i].z); p.h[3] = __float2bfloat16(v[i].w);
            ((ushort4*)xnp)[i] = p.u;
        }
        s2 += __shfl_xor(s2, 1); s2 += __shfl_xor(s2, 2);
        q2 += __shfl_xor(q2, 1); q2 += __shfl_xor(q2, 2);
        const float mu2 = s2 * (1.f / CDIM);
        const float rs2 = rsqrtf(q2 * (1.f / CDIM) - mu2 * mu2 + 1e-5f);

        // ln2 -> As fragment layout: slot=(k>>5)*4+((k>>3)&3), elem k&7
#pragma unroll
        for (int i = 0; i < 16; ++i) {
            const int col0 = part * 64 + i * 4;
            const float4 G = ((const float4*)(ln2g + part * 64))[i];
            const float4 B = ((const float4*)(ln2b + part * 64))[i];
            union { ushort4 u; __hip_bfloat16 h[4]; } p;
            p.h[0] = __float2bfloat16((v[i].x - mu2) * rs2 * G.x + B.x);
            p.h[1] = __float2bfloat16((v[i].y - mu2) * rs2 * G.y + B.y);
            p.h[2] = __float2bfloat16((v[i].z - mu2) * rs2 * G.z + B.z);
            p.h[3] = __float2bfloat16((v[i].w - mu2) * rs2 * G.w + B.w);
            const int idx16 = ((col0 >> 5) * 4 + ((col0 >> 3) & 3)) * 128 + row;
            *(ushort4*)(As + idx16 * 8 + (col0 & 7)) = p.u;
        }
    }
    __syncthreads();

    // ---------------- MLP phase (8 chunks of 128 hidden cols) -------------
    const int wave = tid >> 6, lane = tid & 63;
    const int wm = wave >> 2, wn = wave & 3;   // 2 row-groups x 4 col-groups
    const int fr = lane & 15, fq = lane >> 4;

    floatx4 acc2[4][4] = {};
    short8 b1f[8][2];   // fc1 weight frags: 64 VGPR
    short8 b2f[4][4];   // fc2 weight frags: 64 VGPR

    const __hip_bfloat16* w1base = w1t + (wn * 32 + fr) * 256 + fq * 8;
    const __hip_bfloat16* w2base = w2t + (wn * 64 + fr) * 1024 + fq * 8;

#define LOADB1(c)                                                             \
    {                                                                         \
        const __hip_bfloat16* p = w1base + (c) * 128 * 256;                   \
        _Pragma("unroll")                                                     \
        for (int kf = 0; kf < 8; ++kf)                                        \
            _Pragma("unroll")                                                 \
            for (int nf = 0; nf < 2; ++nf)                                    \
                b1f[kf][nf] = *(const short8*)(p + nf * 16 * 256 + kf * 32);  \
        __builtin_amdgcn_sched_barrier(0);                                    \
    }
#define LOADB2(c)                                                             \
    {                                                                         \
        const __hip_bfloat16* p = w2base + (c) * 128;                         \
        _Pragma("unroll")                                                     \
        for (int kf = 0; kf < 4; ++kf)                                        \
            _Pragma("unroll")                                                 \
            for (int nf = 0; nf < 4; ++nf)                                    \
                b2f[kf][nf] = *(const short8*)(p + nf * 16 * 1024 + kf * 32); \
        __builtin_amdgcn_sched_barrier(0);                                    \
    }

    // fc1: rows wm*64..+64 (mf=4), chunk cols wn*32..+32 (nf=2), K=256 (kf=8)
#define FC1_GELU(c)                                                           \
    {                                                                         \
        floatx4 acc1[4][2] = {};                                              \
        _Pragma("unroll")                                                     \
        for (int kf = 0; kf < 8; ++kf) {                                      \
            short8 a[4];                                                      \
            _Pragma("unroll")                                                 \
            for (int mf = 0; mf < 4; ++mf)                                    \
                a[mf] = *(const short8*)(                                     \
                    As + ((kf * 4 + fq) * 128 + wm * 64 + mf * 16 + fr) * 8); \
            _Pragma("unroll")                                                 \
            for (int mf = 0; mf < 4; ++mf)                                    \
                _Pragma("unroll")                                             \
                for (int nf = 0; nf < 2; ++nf)                                \
                    acc1[mf][nf] = __builtin_amdgcn_mfma_f32_16x16x32_bf16(   \
                        a[mf], b1f[kf][nf], acc1[mf][nf], 0, 0, 0);           \
        }                                                                     \
        __hip_bfloat16* hb = Hs[(c) & 1];                                     \
        _Pragma("unroll")                                                     \
        for (int nf = 0; nf < 2; ++nf) {                                      \
            const int   col = wn * 32 + nf * 16 + fr;                         \
            const float bb  = fb1[(c) * 128 + col];                           \
            __hip_bfloat16* hp =                                              \
                hb + (((col >> 5) * 4 + ((col >> 3) & 3)) * 128) * 8 + (col & 7); \
            _Pragma("unroll")                                                 \
            for (int mf = 0; mf < 4; ++mf)                                    \
                _Pragma("unroll")                                             \
                for (int j = 0; j < 4; ++j) {                                 \
                    const int row = wm * 64 + mf * 16 + fq * 4 + j;           \
                    hp[row * 8] =                                             \
                        __float2bfloat16(gelu_fast(acc1[mf][nf][j] + bb));    \
                }                                                             \
        }                                                                     \
    }

    // fc2: rows wm*64..+64 (mf=4), out cols wn*64..+64 (nf=4), chunk K=128 (kf=4)
#define FC2(c)                                                                \
    {                                                                         \
        const __hip_bfloat16* hb = Hs[(c) & 1];                               \
        _Pragma("unroll")                                                     \
        for (int kf = 0; kf < 4; ++kf) {                                      \
            short8 ha[4];                                                     \
            _Pragma("unroll")                                                 \
            for (int mf = 0; mf < 4; ++mf)                                    \
                ha[mf] = *(const short8*)(                                    \
                    hb + ((kf * 4 + fq) * 128 + wm * 64 + mf * 16 + fr) * 8); \
            _Pragma("unroll")                                                 \
            for (int mf = 0; mf < 4; ++mf)                                    \
                _Pragma("unroll")                                             \
                for (int nf = 0; nf < 4; ++nf)                                \
                    acc2[mf][nf] = __builtin_amdgcn_mfma_f32_16x16x32_bf16(   \
                        ha[mf], b2f[kf][nf], acc2[mf][nf], 0, 0, 0);          \
        }                                                                     \
    }

    // prologue: chunk 0
    LOADB1(0);
    FC1_GELU(0);
    LOADB2(0);
    __syncthreads();

#pragma unroll 1
    for (int c = 1; c < 8; ++c) {
        LOADB1(c);          // w1 frags for c in flight during fc2(c-1)
        FC2(c - 1);
        FC1_GELU(c);
        LOADB2(c);          // w2 frags for c in flight across the barrier
        __syncthreads();
    }
    FC2(7);

    // ---------------- epilogue: out = acc2 + b2 + xn ----------------
#pragma unroll
    for (int nf = 0; nf < 4; ++nf) {
        const int   oc = wn * 64 + nf * 16 + fr;
        const float bb = fb2[oc];
#pragma unroll
        for (int mf = 0; mf < 4; ++mf)
#pragma unroll
            for (int j = 0; j < 4; ++j) {
                const long row = m0 + wm * 64 + mf * 16 + fq * 4 + j;
                out[row * CDIM + oc] = acc2[mf][nf][j] + bb
                                     + __bfloat162float(xnbuf[row * CDIM + oc]);
            }
    }
#undef LOADB1
#undef LOADB2
#undef FC1_GELU
#undef FC2
}

// ---------------------------------------------------------------------------
extern "C" void kernel_launch(void* const* d_in, const int* in_sizes, int n_in,
                              void* d_out, int out_size, void* d_ws, size_t ws_size,
                              hipStream_t stream)
{
    const float* x    = (const float*)d_in[0];
    const float* ln1g = (const float*)d_in[1];
    const float* ln1b = (const float*)d_in[2];
    const float* ln2g = (const float*)d_in[3];
    const float* ln2b = (const float*)d_in[4];
    const float* w1   = (const float*)d_in[5];
    const float* b1   = (const float*)d_in[6];
    const float* w2   = (const float*)d_in[7];
    const float* b2   = (const float*)d_in[8];
    float* out = (float*)d_out;

    // workspace
    char* ws = (char*)d_ws;
    __hip_bfloat16* xnbuf = (__hip_bfloat16*)ws;                 //  67,108,864 B
    __hip_bfloat16* w1t   = (__hip_bfloat16*)(ws + 67108864);    //     524,288 B
    __hip_bfloat16* w2t   = (__hip_bfloat16*)(ws + 67633152);    //     524,288 B

    // weight transpose + bf16 convert (w1t[1024][256], w2t[256][1024])
    transpose_cvt<<<(CDIM * HDIM) / 256, 256, 0, stream>>>(w1, w1t, CDIM, HDIM);
    transpose_cvt<<<(CDIM * HDIM) / 256, 256, 0, stream>>>(w2, w2t, HDIM, CDIM);

    // fully fused block
    swin_fused<<<M_TOTAL / 128, 512, 0, stream>>>(
        x, ln1g, ln1b, ln2g, ln2b, w1t, b1, w2t, b2, xnbuf, out);
}